// Round 9
// baseline (1025.252 us; speedup 1.0000x reference)
//
#include <hip/hip_runtime.h>
#include <math.h>

#define S_LEN 100
#define NCAT  18

typedef __attribute__((ext_vector_type(8)))  short  short8;
typedef __attribute__((ext_vector_type(16))) float  floatx16;

#define AT_LOADU(p)   __hip_atomic_load((p), __ATOMIC_RELAXED, __HIP_MEMORY_SCOPE_AGENT)
#define AT_STORE(p,v) __hip_atomic_store((p),(v), __ATOMIC_RELAXED, __HIP_MEMORY_SCOPE_AGENT)

// ws layout: 12 tagged-h arrays, 64 KB each: base = ((lstm*2+layer)*3 + slot)*65536.
// Array element: u64 at [(mq*64 + b)*2 + j] = h_{4mq+2j} | h_{4mq+2j+1}<<16 | epoch<<48.
// Epochs 1..100; slot = epoch % 3; slot-0 zeroed with tag 0 (initial state).
// All traffic relaxed agent-scope (sc1, IF-coherent). NO barriers, NO fences:
// freshness is per-u64 via the embedded tag; 3-slot rotation + layer0's lag-2
// throttle on h1 make overwrite provably ordered after all reads (transitive
// dependency through the tags themselves).

struct Params {
  const int* ivu; const int* ivo;
  const float* lro; const float* lru;
  const float* VE;
  const float* W[4][2];   // [inst][part]; inst: bit0=lstm, bit1=layer
  const float* b0[4]; const float* b1[4];
  const float* roW; const float* rob;
  const float* ruW; const float* rub;
  float* ws; float* out;
};

__device__ __forceinline__ unsigned short f2bf(float f) {
  unsigned u = __builtin_bit_cast(unsigned, f);
  u += 0x7FFFu + ((u >> 16) & 1u);          // RNE
  return (unsigned short)(u >> 16);
}
__device__ __forceinline__ float bf2f(unsigned short h) {
  unsigned u = ((unsigned)h) << 16;
  return __builtin_bit_cast(float, u);
}
__device__ __forceinline__ short8 pack8(float4 a, float4 b) {
  short8 r;
  r[0] = (short)f2bf(a.x); r[1] = (short)f2bf(a.y);
  r[2] = (short)f2bf(a.z); r[3] = (short)f2bf(a.w);
  r[4] = (short)f2bf(b.x); r[5] = (short)f2bf(b.y);
  r[6] = (short)f2bf(b.z); r[7] = (short)f2bf(b.w);
  return r;
}
__device__ __forceinline__ unsigned long long* AB(char* wsb, int lstm, int layer, int slot) {
  return (unsigned long long*)(wsb + (((((lstm << 1) | layer) * 3) + slot) << 16));
}

__global__ void init_k(char* wsb, float* out) {
  const int idx = blockIdx.x * 256 + threadIdx.x;       // 0..32767
  const int a = idx >> 13, off = idx & 8191;            // a = lstm*2+layer
  ((unsigned long long*)(wsb + ((a * 3) << 16)))[off] = 0ull;   // slot 0: h=0, tag=0
  if (idx == 0) out[64] = 0.f;
}

// 64 WGs x 256 thr (4 waves), free-running dataflow. WG (inst, wg) owns
// gate-rows r = g*16+m, R = g*256 + wg*16 + m, K = 512.
// LDS fragment order: 16B block index (s*2+half)*64 + (row|col) — every
// ds_read_b128 is lane-consecutive (conflict-free).
__global__ __launch_bounds__(256, 1) void lstm_all(Params P) {
  __shared__ short Afrag[32768];       // 64 KB weights, fragment order
  __shared__ short Bfrag[32768];       // 64 KB x_t, fragment order
  __shared__ float gatebuf[64 * 64];   // 16 KB
  __shared__ float cst[16 * 64];       // 4 KB
  __shared__ float bias_l[64];

  const int tid  = threadIdx.x;
  const int lane = tid & 63;
  const int wave = tid >> 6;
  const int blk  = blockIdx.x;
  const int inst = blk >> 4;            // 0=vu-L0 1=vo-L0 2=vu-L1 3=vo-L1
  const int wg   = blk & 15;
  const int lstm = inst & 1;
  const int layer = inst >> 1;

  char* wsb = (char*)P.ws;
  const int jt = wave >> 1, bt = wave & 1;
  const int half = lane >> 5;
  const int bl   = bt * 32 + (lane & 31);
  const int rl2  = jt * 32 + (lane & 31);

  // ---- one-time: stage A (weights) into fragment-order LDS ----
  {
    const int rl = tid >> 2;            // 0..63
    const int q  = tid & 3;
    const int R  = (rl >> 4) * 256 + wg * 16 + (rl & 15);
    const float* wih = P.W[inst][0] + (size_t)R * 256;
    const float* whh = P.W[inst][1] + (size_t)R * 256;
    #pragma unroll
    for (int kb = q * 16; kb < q * 16 + 16; ++kb) {   // kb = k/8
      const int k0 = kb * 8;
      const float* src = (k0 < 256 ? wih + k0 : whh + (k0 - 256));
      float4 v0 = *(const float4*)src;
      float4 v1 = *(const float4*)(src + 4);
      const int s_ = k0 >> 4, hf = (k0 >> 3) & 1;
      *(short8*)&Afrag[((s_ * 2 + hf) * 64 + rl) * 8] = pack8(v0, v1);
    }
  }
  if (tid < 64) {
    const int R = (tid >> 4) * 256 + wg * 16 + (tid & 15);
    bias_l[tid] = P.b0[inst][R] + P.b1[inst][R];
  }
  for (int i = tid; i < 16 * 64; i += 256) cst[i] = 0.f;

  const int* __restrict__ idxp = lstm ? P.ivo : P.ivu;

  int slot = 1;                         // s % 3, maintained incrementally
  for (int s = 1; s <= S_LEN; ++s) {
    const int slot_m1 = (slot + 2) % 3; // (s-1) % 3
    unsigned long long vA0[16], vA1[16], vB0[16], vB1[16];
    float4 e[16];
    const unsigned long long* srcA = nullptr;
    unsigned wantA = 0;

    // ---- issue all staging loads (deep, independent) ----
    if (layer == 0) {
      const int vb = tid >> 2, vq = tid & 3;
      const int row = idxp[vb * S_LEN + (s - 1)];
      const float* __restrict__ vr = P.VE + (size_t)row * 256 + vq * 64;
      #pragma unroll
      for (int j = 0; j < 16; ++j) e[j] = *(const float4*)(vr + j * 4);
    } else {
      srcA = AB(wsb, lstm, 0, slot);                 // y0_s, tag s
      wantA = (unsigned)s;
      #pragma unroll
      for (int j = 0; j < 16; ++j) {
        const int p = tid + j * 256;
        vA0[j] = AT_LOADU(srcA + p * 2);
        vA1[j] = AT_LOADU(srcA + p * 2 + 1);
      }
    }
    const unsigned long long* srcB = AB(wsb, lstm, layer, slot_m1);  // h_{s-1}, tag s-1
    const unsigned wantB = (unsigned)(s - 1);
    #pragma unroll
    for (int j = 0; j < 16; ++j) {
      const int p = tid + j * 256;
      vB0[j] = AT_LOADU(srcB + p * 2);
      vB1[j] = AT_LOADU(srcB + p * 2 + 1);
    }

    // ---- tag-check retry (the poll IS the load) ----
    for (;;) {
      bool again = false;
      #pragma unroll
      for (int j = 0; j < 16; ++j) {
        const int p = tid + j * 256;
        if (layer == 1) {
          if ((unsigned)(vA0[j] >> 48) != wantA) { vA0[j] = AT_LOADU(srcA + p * 2);     again = true; }
          if ((unsigned)(vA1[j] >> 48) != wantA) { vA1[j] = AT_LOADU(srcA + p * 2 + 1); again = true; }
        }
        if ((unsigned)(vB0[j] >> 48) != wantB) { vB0[j] = AT_LOADU(srcB + p * 2);     again = true; }
        if ((unsigned)(vB1[j] >> 48) != wantB) { vB1[j] = AT_LOADU(srcB + p * 2 + 1); again = true; }
      }
      if (!__any(again)) break;
    }

    // ---- layer0 throttle: don't run >2 ahead of layer1 (slot-reuse safety) ----
    if (layer == 0 && tid == 0 && s >= 3) {
      const unsigned long long* thr = AB(wsb, lstm, 1, (s - 2) % 3) + (wg * 4 * 64) * 2;
      while ((unsigned)(AT_LOADU(thr) >> 48) != (unsigned)(s - 2)) { }
    }

    // ---- unpack into fragment-order Bfrag ----
    if (layer == 0) {
      const int vb = tid >> 2, vq = tid & 3;
      #pragma unroll
      for (int jb = 0; jb < 8; ++jb) {
        const int k0 = vq * 64 + jb * 8;
        const int s_ = k0 >> 4, hf = (k0 >> 3) & 1;
        *(short8*)&Bfrag[((s_ * 2 + hf) * 64 + vb) * 8] = pack8(e[jb * 2], e[jb * 2 + 1]);
      }
    } else {
      #pragma unroll
      for (int j = 0; j < 16; ++j) {
        const int p = tid + j * 256, mq = p >> 6, b = p & 63;
        const unsigned long long d =
            (vA0[j] & 0xFFFFFFFFull) | ((vA1[j] & 0xFFFFFFFFull) << 32);
        const int k0 = mq * 4;
        const int s_ = k0 >> 4, hf = (k0 >> 3) & 1;
        *(unsigned long long*)&Bfrag[((s_ * 2 + hf) * 64 + b) * 8 + (k0 & 7)] = d;
      }
    }
    #pragma unroll
    for (int j = 0; j < 16; ++j) {
      const int p = tid + j * 256, mq = p >> 6, b = p & 63;
      const unsigned long long d =
          (vB0[j] & 0xFFFFFFFFull) | ((vB1[j] & 0xFFFFFFFFull) << 32);
      const int k0 = mq * 4;
      const int s_ = 16 + (k0 >> 4), hf = (k0 >> 3) & 1;
      *(unsigned long long*)&Bfrag[((s_ * 2 + hf) * 64 + b) * 8 + (k0 & 7)] = d;
    }
    __syncthreads();

    // ---- MFMA: 32 x 32x32x16, two independent accumulator chains ----
    floatx16 ae, ao;
    #pragma unroll
    for (int r = 0; r < 16; ++r) { ae[r] = 0.f; ao[r] = 0.f; }
    #pragma unroll
    for (int ss = 0; ss < 32; ss += 2) {
      short8 a0 = *(const short8*)&Afrag[(((ss    ) * 2 + half) * 64 + rl2) * 8];
      short8 b0 = *(const short8*)&Bfrag[(((ss    ) * 2 + half) * 64 + bl ) * 8];
      short8 a1 = *(const short8*)&Afrag[(((ss + 1) * 2 + half) * 64 + rl2) * 8];
      short8 b1 = *(const short8*)&Bfrag[(((ss + 1) * 2 + half) * 64 + bl ) * 8];
      ae = __builtin_amdgcn_mfma_f32_32x32x16_bf16(a0, b0, ae, 0, 0, 0);
      ao = __builtin_amdgcn_mfma_f32_32x32x16_bf16(a1, b1, ao, 0, 0, 0);
    }
    #pragma unroll
    for (int r = 0; r < 16; ++r) {
      const int row = (r & 3) + 8 * (r >> 2) + 4 * half;   // C/D layout (m74/m101)
      gatebuf[(jt * 32 + row) * 64 + bl] = ae[r] + ao[r];
    }
    __syncthreads();

    // ---- activations + tagged h stores (no drain, no flag) ----
    {
      const int b = tid & 63, mq4 = tid >> 6;
      unsigned short hv[4];
      #pragma unroll
      for (int i = 0; i < 4; ++i) {
        const int m = mq4 * 4 + i;
        const float g0 = gatebuf[(0 * 16 + m) * 64 + b] + bias_l[0 * 16 + m];
        const float g1 = gatebuf[(1 * 16 + m) * 64 + b] + bias_l[1 * 16 + m];
        const float g2 = gatebuf[(2 * 16 + m) * 64 + b] + bias_l[2 * 16 + m];
        const float g3 = gatebuf[(3 * 16 + m) * 64 + b] + bias_l[3 * 16 + m];
        const float ig = 1.f / (1.f + __expf(-g0));
        const float fg = 1.f / (1.f + __expf(-g1));
        const float gg = tanhf(g2);
        const float og = 1.f / (1.f + __expf(-g3));
        const float c  = fg * cst[m * 64 + b] + ig * gg;
        cst[m * 64 + b] = c;
        hv[i] = f2bf(og * tanhf(c));
      }
      const unsigned long long tag = ((unsigned long long)s) << 48;
      unsigned long long* dst = AB(wsb, lstm, layer, slot) + ((wg * 4 + mq4) * 64 + b) * 2;
      AT_STORE(dst,     (unsigned long long)hv[0] | ((unsigned long long)hv[1] << 16) | tag);
      AT_STORE(dst + 1, (unsigned long long)hv[2] | ((unsigned long long)hv[3] << 16) | tag);
    }
    slot = (slot == 2) ? 0 : slot + 1;
  }
}

// head: 64 blocks (one per batch) x 64 threads; reads tagged h1 arrays (slot 100%3=1)
__global__ __launch_bounds__(64) void head_kernel(Params P) {
  __shared__ float enc[256];
  __shared__ float hu[256], ho[256];
  __shared__ float dec[NCAT];
  const int b = blockIdx.x, t = threadIdx.x;
  char* wsb = (char*)P.ws;
  const unsigned long long* avu = AB(wsb, 0, 1, 1);
  const unsigned long long* avo = AB(wsb, 1, 1, 1);

  for (int k = t; k < 256; k += 64) {
    const int idx = ((k >> 2) * 64 + b) * 2 + ((k >> 1) & 1);
    const int sh = 16 * (k & 1);
    hu[k] = bf2f((unsigned short)(avu[idx] >> sh));
    ho[k] = bf2f((unsigned short)(avo[idx] >> sh));
    float s = P.rob[k];
    for (int j = 0; j < NCAT; ++j) s = fmaf(P.lro[b * NCAT + j], P.roW[k * NCAT + j], s);
    enc[k] = fmaxf(s, 0.f);
  }
  __syncthreads();
  for (int n = 0; n < NCAT; ++n) {
    const float* __restrict__ wr = P.ruW + n * 768;
    float s = 0.f;
    for (int k = t; k < 256; k += 64) {
      s = fmaf(hu[k],  wr[k],       s);
      s = fmaf(ho[k],  wr[256 + k], s);
      s = fmaf(enc[k], wr[512 + k], s);
    }
    for (int off = 32; off; off >>= 1) s += __shfl_down(s, off, 64);
    if (t == 0) dec[n] = s + P.rub[n];
  }
  __syncthreads();
  if (t == 0) {
    float M = dec[0];
    for (int j = 1; j < NCAT; ++j) M = fmaxf(M, dec[j]);
    float Ssum = 0.f;
    for (int j = 0; j < NCAT; ++j) Ssum += expf(dec[j] - M);
    const float lse = M + logf(Ssum);
    float neg = 0.f, kl = 0.f;
    for (int j = 0; j < NCAT; ++j) {
      const float lp = dec[j] - lse;
      const float q  = P.lru[b * NCAT + j];
      neg -= q * lp;
      kl  += q * (logf(q) - lp);
    }
    P.out[b] = neg;
    atomicAdd(&P.out[64], kl * 1.4426950408889634f * (1.f / 64.f));
  }
}

extern "C" void kernel_launch(void* const* d_in, const int* in_sizes, int n_in,
                              void* d_out, int out_size, void* d_ws, size_t ws_size,
                              hipStream_t stream) {
  Params P;
  P.ivu = (const int*)d_in[0];
  P.ivo = (const int*)d_in[1];
  P.lro = (const float*)d_in[2];
  if (in_sizes[3] >= in_sizes[4]) { P.VE = (const float*)d_in[3]; P.lru = (const float*)d_in[4]; }
  else                            { P.VE = (const float*)d_in[4]; P.lru = (const float*)d_in[3]; }
  // inst: 0 = vu-L0, 1 = vo-L0, 2 = vu-L1, 3 = vo-L1
  P.W[0][0] = (const float*)d_in[5];  P.W[0][1] = (const float*)d_in[6];
  P.b0[0]   = (const float*)d_in[7];  P.b1[0]   = (const float*)d_in[8];
  P.W[2][0] = (const float*)d_in[9];  P.W[2][1] = (const float*)d_in[10];
  P.b0[2]   = (const float*)d_in[11]; P.b1[2]   = (const float*)d_in[12];
  P.W[1][0] = (const float*)d_in[13]; P.W[1][1] = (const float*)d_in[14];
  P.b0[1]   = (const float*)d_in[15]; P.b1[1]   = (const float*)d_in[16];
  P.W[3][0] = (const float*)d_in[17]; P.W[3][1] = (const float*)d_in[18];
  P.b0[3]   = (const float*)d_in[19]; P.b1[3]   = (const float*)d_in[20];
  P.roW = (const float*)d_in[21]; P.rob = (const float*)d_in[22];
  P.ruW = (const float*)d_in[23]; P.rub = (const float*)d_in[24];
  P.ws  = (float*)d_ws;
  P.out = (float*)d_out;

  init_k<<<128, 256, 0, stream>>>((char*)d_ws, P.out);

  void* args[] = { &P };
  hipLaunchCooperativeKernel((void*)lstm_all, dim3(64), dim3(256), args, 0, stream);
  head_kernel<<<64, 64, 0, stream>>>(P);
}